// Round 2
// baseline (629.824 us; speedup 1.0000x reference)
//
#include <hip/hip_runtime.h>
#include <hip/hip_bf16.h>
#include <stdint.h>

// Problem: ComplexDepthwiseBatchNorm  N=16384, C=8, F=257
// Layout: x[N][C*F] row-major; NCOLS = 2056 columns per row.
// Dtype of x / W / out is detected ON DEVICE (bf16 vs fp32) — see detect_kernel.
#define NROWS   16384
#define NCOLS   2056
#define NG      257          // groups of 8 elements per row (2056/8)
#define EPSV    1e-6f
#define DELTA_MAX 1e8f

__device__ __forceinline__ float bf_lo(uint32_t u) {
    return __builtin_bit_cast(float, u << 16);
}
__device__ __forceinline__ float bf_hi(uint32_t u) {
    return __builtin_bit_cast(float, u & 0xffff0000u);
}
__device__ __forceinline__ float bf1(uint16_t u) {
    return __builtin_bit_cast(float, (uint32_t)u << 16);
}
// round-to-nearest-even bf16 pair pack: lo -> bits[15:0], hi -> bits[31:16]
__device__ __forceinline__ uint32_t bf16pair(float lo, float hi) {
    uint32_t ul = __builtin_bit_cast(uint32_t, lo);
    uint32_t uh = __builtin_bit_cast(uint32_t, hi);
    ul = (ul + 0x7fffu + ((ul >> 16) & 1u)) >> 16;
    uh = (uh + 0x7fffu + ((uh >> 16) & 1u)) & 0xffff0000u;
    return ul | uh;
}

// ---------------- Pass 0: dtype detection ----------------
// bf16 pair: low 16 bits are a bf16 whose exponent field (u>>7)&0xFF lies in
// the "plausible data" band for ~all normal samples. fp32: bits[14:7] are
// uniform mantissa bits (~12.5% in band). Wrr==1.0 is deterministic:
// bf16 pair 0x3F803F80 -> field 127 (in band); fp32 0x3F800000 -> field 0.
// flags[0]=1 iff x is fp32; flags[1]=1 iff W/B are fp32.
__global__ __launch_bounds__(512) void detect_kernel(
    const uint32_t* __restrict__ xr_u, const uint32_t* __restrict__ wrr_u,
    int* __restrict__ flags)
{
    __shared__ int cnt[2];
    if (threadIdx.x < 2) cnt[threadIdx.x] = 0;
    __syncthreads();
    const int part = threadIdx.x >> 8;                    // 0: x, 1: Wrr
    const uint32_t u = part ? wrr_u[threadIdx.x & 255] : xr_u[threadIdx.x & 255];
    const uint32_t e = (u >> 7) & 0xFFu;
    const int ok = (e >= 100u && e <= 131u) ? 1 : 0;
    atomicAdd(&cnt[part], ok);
    __syncthreads();
    if (threadIdx.x == 0) {
        flags[0] = (cnt[0] < 128) ? 1 : 0;
        flags[1] = (cnt[1] < 128) ? 1 : 0;
    }
}

// ---------------- Pass 1: per-column sums (column-stationary) ----------------
// grid 257 x block 256 => T = 65792 = 256*257 threads (bijection tid->(r0,c)).
// Each thread owns columns [8c, 8c+8) and strides rows r0 + 256*k, k<64.
__global__ __launch_bounds__(256) void stats_kernel(
    const void* __restrict__ xr_p, const void* __restrict__ xi_p,
    const int* __restrict__ flags, float* __restrict__ sums)
{
    const int tid = blockIdx.x * 256 + threadIdx.x;
    const int c  = tid % NG;
    const int r0 = tid / NG;            // [0,256)
    float sr[8], si[8], srr[8], sri[8], sii[8];
    #pragma unroll
    for (int j = 0; j < 8; ++j) { sr[j]=0.f; si[j]=0.f; srr[j]=0.f; sri[j]=0.f; sii[j]=0.f; }

    if (flags[0]) {
        // -------- fp32 path: row = 2056 floats = 514 float4 --------
        const float4* xr4 = (const float4*)xr_p;
        const float4* xi4 = (const float4*)xi_p;
        #pragma unroll 2
        for (int k = 0; k < 64; ++k) {
            const size_t g = (size_t)(r0 + (k << 8)) * 514 + 2 * c;
            const float4 a0 = xr4[g], a1 = xr4[g + 1];
            const float4 b0 = xi4[g], b1 = xi4[g + 1];
            const float xrv[8] = {a0.x,a0.y,a0.z,a0.w,a1.x,a1.y,a1.z,a1.w};
            const float xiv[8] = {b0.x,b0.y,b0.z,b0.w,b1.x,b1.y,b1.z,b1.w};
            #pragma unroll
            for (int j = 0; j < 8; ++j) {
                sr[j]  += xrv[j];
                si[j]  += xiv[j];
                srr[j] += xrv[j]*xrv[j];
                sri[j] += xrv[j]*xiv[j];
                sii[j] += xiv[j]*xiv[j];
            }
        }
    } else {
        // -------- bf16 path: row = 2056 bf16 = 257 uint4 --------
        const uint4* xr4 = (const uint4*)xr_p;
        const uint4* xi4 = (const uint4*)xi_p;
        #pragma unroll 2
        for (int k = 0; k < 64; ++k) {
            const size_t g = (size_t)(r0 + (k << 8)) * NG + c;
            const uint4 a = xr4[g];
            const uint4 b = xi4[g];
            const uint32_t au[4] = {a.x, a.y, a.z, a.w};
            const uint32_t bu[4] = {b.x, b.y, b.z, b.w};
            #pragma unroll
            for (int j = 0; j < 4; ++j) {
                const float r_0 = bf_lo(au[j]), r_1 = bf_hi(au[j]);
                const float i_0 = bf_lo(bu[j]), i_1 = bf_hi(bu[j]);
                sr [2*j]   += r_0;        si [2*j]   += i_0;
                srr[2*j]   += r_0*r_0;    sri[2*j]   += r_0*i_0;    sii[2*j]   += i_0*i_0;
                sr [2*j+1] += r_1;        si [2*j+1] += i_1;
                srr[2*j+1] += r_1*r_1;    sri[2*j+1] += r_1*i_1;    sii[2*j+1] += i_1*i_1;
            }
        }
    }

    const int col = c * 8;
    #pragma unroll
    for (int j = 0; j < 8; ++j) {
        atomicAdd(&sums[0*NCOLS + col + j], sr [j]);
        atomicAdd(&sums[1*NCOLS + col + j], si [j]);
        atomicAdd(&sums[2*NCOLS + col + j], srr[j]);
        atomicAdd(&sums[3*NCOLS + col + j], sri[j]);
        atomicAdd(&sums[4*NCOLS + col + j], sii[j]);
    }
}

// ---------------- Pass 2: sums -> per-column coefficients ----------------
// coef[0..5][j] = Zrr, Zri, Zir, Zii, Cr, Ci  with means+bias folded in.
__global__ __launch_bounds__(256) void coef_kernel(
    const float* __restrict__ sums,
    const void* __restrict__ Wrr_p, const void* __restrict__ Wri_p,
    const void* __restrict__ Wii_p, const void* __restrict__ Br_p,
    const void* __restrict__ Bi_p,
    const int* __restrict__ flags, float* __restrict__ coef)
{
    const int j = blockIdx.x * 256 + threadIdx.x;
    if (j >= NCOLS) return;
    const float invN = 1.0f / (float)NROWS;
    const float Mr  = sums[0*NCOLS+j] * invN;
    const float Mi  = sums[1*NCOLS+j] * invN;
    const float Vrr = sums[2*NCOLS+j] * invN - Mr * Mr;
    const float Vri = sums[3*NCOLS+j] * invN - Mr * Mi;
    const float Vii = sums[4*NCOLS+j] * invN - Mi * Mi;
    const float tau   = Vrr + Vii;
    const float delta = fminf(fmaxf(Vrr * Vii - Vri * Vri, EPSV), DELTA_MAX);
    const float s   = sqrtf(delta);
    const float t   = sqrtf(tau + 2.0f * s);
    const float rst = 1.0f / (s * t);
    const float Urr = (s + Vii) * rst;
    const float Uii = (s + Vrr) * rst;
    const float Uri = -Vri * rst;

    float wrr, wri, wii, br, bi;
    if (flags[1]) {
        wrr = ((const float*)Wrr_p)[j];  wri = ((const float*)Wri_p)[j];
        wii = ((const float*)Wii_p)[j];
        br  = ((const float*)Br_p)[j];   bi  = ((const float*)Bi_p)[j];
    } else {
        wrr = bf1(((const uint16_t*)Wrr_p)[j]);  wri = bf1(((const uint16_t*)Wri_p)[j]);
        wii = bf1(((const uint16_t*)Wii_p)[j]);
        br  = bf1(((const uint16_t*)Br_p)[j]);   bi  = bf1(((const uint16_t*)Bi_p)[j]);
    }
    const float Zrr = wrr * Urr + wri * Uri;
    const float Zri = wrr * Uri + wri * Uii;
    const float Zir = wri * Urr + wii * Uri;
    const float Zii = wri * Uri + wii * Uii;
    coef[0*NCOLS+j] = Zrr;
    coef[1*NCOLS+j] = Zri;
    coef[2*NCOLS+j] = Zir;
    coef[3*NCOLS+j] = Zii;
    coef[4*NCOLS+j] = br - Zrr * Mr - Zri * Mi;
    coef[5*NCOLS+j] = bi - Zir * Mr - Zii * Mi;
}

// ---------------- Pass 3: apply (column-stationary, coeffs in regs) ----------
// grid 514 x block 256 => T = 131584 = 512*257. r0 in [0,512), 32 iterations.
__global__ __launch_bounds__(256) void apply_kernel(
    const void* __restrict__ xr_p, const void* __restrict__ xi_p,
    const float* __restrict__ coef, const int* __restrict__ flags,
    void* __restrict__ out_p)
{
    const int tid = blockIdx.x * 256 + threadIdx.x;
    const int c  = tid % NG;
    const int r0 = tid / NG;            // [0,512)
    const int col = c * 8;

    float Z[6][8];
    #pragma unroll
    for (int t = 0; t < 6; ++t) {
        const float4 lo = *(const float4*)(coef + t*NCOLS + col);
        const float4 hi = *(const float4*)(coef + t*NCOLS + col + 4);
        Z[t][0]=lo.x; Z[t][1]=lo.y; Z[t][2]=lo.z; Z[t][3]=lo.w;
        Z[t][4]=hi.x; Z[t][5]=hi.y; Z[t][6]=hi.z; Z[t][7]=hi.w;
    }

    if (flags[0]) {
        // -------- fp32 path --------
        const float4* xr4 = (const float4*)xr_p;
        const float4* xi4 = (const float4*)xi_p;
        float4* yr4 = (float4*)out_p;
        float4* yi4 = yr4 + (size_t)NROWS * 514;   // yi after N*C*F floats
        #pragma unroll 2
        for (int k = 0; k < 32; ++k) {
            const size_t g = (size_t)(r0 + (k << 9)) * 514 + 2 * c;
            const float4 a0 = xr4[g], a1 = xr4[g + 1];
            const float4 b0 = xi4[g], b1 = xi4[g + 1];
            const float xrv[8] = {a0.x,a0.y,a0.z,a0.w,a1.x,a1.y,a1.z,a1.w};
            const float xiv[8] = {b0.x,b0.y,b0.z,b0.w,b1.x,b1.y,b1.z,b1.w};
            float yrv[8], yiv[8];
            #pragma unroll
            for (int j = 0; j < 8; ++j) {
                yrv[j] = Z[0][j]*xrv[j] + Z[1][j]*xiv[j] + Z[4][j];
                yiv[j] = Z[2][j]*xrv[j] + Z[3][j]*xiv[j] + Z[5][j];
            }
            yr4[g]     = make_float4(yrv[0], yrv[1], yrv[2], yrv[3]);
            yr4[g + 1] = make_float4(yrv[4], yrv[5], yrv[6], yrv[7]);
            yi4[g]     = make_float4(yiv[0], yiv[1], yiv[2], yiv[3]);
            yi4[g + 1] = make_float4(yiv[4], yiv[5], yiv[6], yiv[7]);
        }
    } else {
        // -------- bf16 path --------
        const uint4* xr4 = (const uint4*)xr_p;
        const uint4* xi4 = (const uint4*)xi_p;
        uint4* yr4 = (uint4*)out_p;
        uint4* yi4 = yr4 + (size_t)NROWS * NG;     // yi after N*C*F bf16
        #pragma unroll 2
        for (int k = 0; k < 32; ++k) {
            const size_t g = (size_t)(r0 + (k << 9)) * NG + c;
            const uint4 a = xr4[g];
            const uint4 b = xi4[g];
            const uint32_t au[4] = {a.x, a.y, a.z, a.w};
            const uint32_t bu[4] = {b.x, b.y, b.z, b.w};
            uint32_t ou[4], pu[4];
            #pragma unroll
            for (int j = 0; j < 4; ++j) {
                const int e0 = 2*j, e1 = 2*j + 1;
                const float xr0 = bf_lo(au[j]), xr1 = bf_hi(au[j]);
                const float xi0 = bf_lo(bu[j]), xi1 = bf_hi(bu[j]);
                const float yr0 = Z[0][e0]*xr0 + Z[1][e0]*xi0 + Z[4][e0];
                const float yi0 = Z[2][e0]*xr0 + Z[3][e0]*xi0 + Z[5][e0];
                const float yr1 = Z[0][e1]*xr1 + Z[1][e1]*xi1 + Z[4][e1];
                const float yi1 = Z[2][e1]*xr1 + Z[3][e1]*xi1 + Z[5][e1];
                ou[j] = bf16pair(yr0, yr1);
                pu[j] = bf16pair(yi0, yi1);
            }
            yr4[g] = make_uint4(ou[0], ou[1], ou[2], ou[3]);
            yi4[g] = make_uint4(pu[0], pu[1], pu[2], pu[3]);
        }
    }
}

extern "C" void kernel_launch(void* const* d_in, const int* in_sizes, int n_in,
                              void* d_out, int out_size, void* d_ws, size_t ws_size,
                              hipStream_t stream)
{
    const void* xr_p = d_in[0];
    const void* xi_p = d_in[1];
    const void* Wrr  = d_in[2];
    const void* Wri  = d_in[3];
    const void* Wii  = d_in[4];
    const void* Br   = d_in[5];
    const void* Bi   = d_in[6];

    float* sums  = (float*)d_ws;             // 5 * 2056 f32
    float* coef  = sums + 5 * NCOLS;         // 6 * 2056 f32
    int*   flags = (int*)(coef + 6 * NCOLS); // 2 ints

    detect_kernel<<<1, 512, 0, stream>>>((const uint32_t*)xr_p, (const uint32_t*)Wrr, flags);
    hipMemsetAsync(sums, 0, 5 * NCOLS * sizeof(float), stream);
    stats_kernel<<<257, 256, 0, stream>>>(xr_p, xi_p, flags, sums);
    coef_kernel<<<(NCOLS + 255) / 256, 256, 0, stream>>>(sums, Wrr, Wri, Wii, Br, Bi, flags, coef);
    apply_kernel<<<514, 256, 0, stream>>>(xr_p, xi_p, coef, flags, d_out);
}